// Round 8
// baseline (221.117 us; speedup 1.0000x reference)
//
#include <hip/hip_runtime.h>
#include <math.h>

#define Bc 2
#define Cc 320
#define Pc 2304
#define HEADSc 8
#define DHc 64
#define INNERc 512
#define Fc 32
#define LN_EPS 1e-5f
#define CHUNKS 18
#define CHUNK_P 128

typedef __attribute__((ext_vector_type(8))) short bf16x8;
typedef __attribute__((ext_vector_type(4))) float f32x4;

static __device__ __forceinline__ ushort f2bf(float x) {
  uint u = __builtin_bit_cast(uint, x);
  u = (u + 0x7fffu + ((u >> 16) & 1u)) >> 16;
  return (ushort)u;
}

// ---------------------------------------------------------------------------
// Transpose+cast tile helper: src fp32 [R][C] -> dst bf16 [C][R]; 64x64
// ---------------------------------------------------------------------------
static __device__ void transpose_tile(const float* __restrict__ src,
                                      ushort* __restrict__ dst, int R, int C,
                                      int r0, int c0, int tid,
                                      float (*t)[65]) {
#pragma unroll
  for (int it = 0; it < 4; ++it) {
    int lin = it * 256 + tid;
    int rr = lin >> 4, c4 = lin & 15;
    float4 v = *(const float4*)(&src[(size_t)(r0 + rr) * C + c0 + c4 * 4]);
    t[rr][c4 * 4 + 0] = v.x; t[rr][c4 * 4 + 1] = v.y;
    t[rr][c4 * 4 + 2] = v.z; t[rr][c4 * 4 + 3] = v.w;
  }
  __syncthreads();
#pragma unroll
  for (int it = 0; it < 2; ++it) {
    int lin = it * 256 + tid;
    int cc = lin >> 3, r8 = lin & 7;
    ushort tmp[8];
#pragma unroll
    for (int j = 0; j < 8; ++j) tmp[j] = f2bf(t[r8 * 8 + j][cc]);
    *(uint4*)(&dst[(size_t)(c0 + cc) * R + r0 + r8 * 8]) = *(const uint4*)tmp;
  }
}

// ---------------------------------------------------------------------------
// 1. ALL prep in one launch (305 blocks):
//    [0,144): activation transpose+cast (LN fused for ehs)
//    [144,184): WvT  [184,224): WoT  [224,304): gfuse Gk/Gq
//    304: zero the arrival counters for kernels 2 and 3
// ---------------------------------------------------------------------------
__global__ __launch_bounds__(256) void prep_all_kernel(
    const float* __restrict__ hs, const float* __restrict__ ehs,
    const float* __restrict__ gamma, const float* __restrict__ beta,
    const float* __restrict__ Wv, const float* __restrict__ Wo,
    const float* __restrict__ exf, const float* __restrict__ Wk,
    const float* __restrict__ dif, const float* __restrict__ Wq,
    ushort* __restrict__ hsT, ushort* __restrict__ ehsT,
    ushort* __restrict__ WvT, ushort* __restrict__ WoT,
    ushort* __restrict__ Gk, ushort* __restrict__ Gq,
    int* __restrict__ counters) {
  __shared__ float smem[6448];
  int idx = blockIdx.x, tid = threadIdx.x;

  if (idx == 304) {
    if (tid < 64) counters[tid] = 0;   // 16 spatial + 36 chanfinal (+pad)
    return;
  }
  if (idx < 144) {
    int pt = idx % 36, z = idx / 36;
    int b = z & 1, which = z >> 1;
    int pos0 = pt * 64;
    const float* src = (which ? ehs : hs) + (size_t)b * Cc * Pc;
    ushort* dst = (which ? ehsT : hsT) + (size_t)b * Pc * Cc;
    float* t = smem;               // [64][65]
    float* s1 = smem + 4160;
    float* s2 = smem + 4416;
    float* lmean = smem + 4672;
    float* lrstd = smem + 4736;
    int lane = tid & 63, g = tid >> 6;
    if (which) {
      const float* base = src + pos0 + lane;
      float sum = 0.f, sq = 0.f;
      for (int c = g * 80; c < g * 80 + 80; ++c) {
        float x = base[(size_t)c * Pc];
        sum += x; sq += x * x;
      }
      s1[g * 64 + lane] = sum; s2[g * 64 + lane] = sq;
      __syncthreads();
      if (tid < 64) {
        float ts = s1[tid] + s1[64 + tid] + s1[128 + tid] + s1[192 + tid];
        float tq = s2[tid] + s2[64 + tid] + s2[128 + tid] + s2[192 + tid];
        float mean = ts / (float)Cc;
        float var = tq / (float)Cc - mean * mean;
        lmean[tid] = mean;
        lrstd[tid] = rsqrtf(var + LN_EPS);
      }
      __syncthreads();
    }
    for (int ct = 0; ct < 5; ++ct) {
      int r0 = ct * 64;
#pragma unroll
      for (int it = 0; it < 4; ++it) {
        int lin = it * 256 + tid;
        int rr = lin >> 4, c4 = lin & 15;
        float4 v = *(const float4*)(&src[(size_t)(r0 + rr) * Pc + pos0 + c4 * 4]);
        t[rr * 65 + c4 * 4 + 0] = v.x; t[rr * 65 + c4 * 4 + 1] = v.y;
        t[rr * 65 + c4 * 4 + 2] = v.z; t[rr * 65 + c4 * 4 + 3] = v.w;
      }
      __syncthreads();
#pragma unroll
      for (int it = 0; it < 2; ++it) {
        int lin = it * 256 + tid;
        int cc = lin >> 3, r8 = lin & 7;
        float m_ = which ? lmean[cc] : 0.f, rs_ = which ? lrstd[cc] : 1.f;
        ushort tmp[8];
#pragma unroll
        for (int j = 0; j < 8; ++j) {
          int ch = r8 * 8 + j;
          float x = t[ch * 65 + cc];
          float val = which ? (x - m_) * rs_ * gamma[r0 + ch] + beta[r0 + ch] : x;
          tmp[j] = f2bf(val);
        }
        *(uint4*)(&dst[(size_t)(pos0 + cc) * Cc + r0 + r8 * 8]) =
            *(const uint4*)tmp;
      }
      __syncthreads();
    }
  } else {
    int idx2 = idx - 144;
    if (idx2 < 40) {
      transpose_tile(Wv, WvT, Cc, INNERc, (idx2 / 8) * 64, (idx2 % 8) * 64,
                     tid, (float(*)[65])smem);
    } else if (idx2 < 80) {
      int i = idx2 - 40;
      transpose_tile(Wo, WoT, INNERc, Cc, (i / 5) * 64, (i % 5) * 64, tid,
                     (float(*)[65])smem);
    } else {
      int i = idx2 - 80;
      int c0 = (i % 5) * 64, h = (i / 5) % 8, zz = i / 40;
      const float* filt = zz ? dif : exf;
      const float* W = zz ? Wq : Wk;
      ushort* G = zz ? Gq : Gk;
      float (*ef)[66] = (float(*)[66])smem;
      float (*wk)[65] = (float(*)[65])(smem + 32 * 66);
      for (int l = tid; l < Fc * DHc; l += 256) {
        int f = l >> 6, d = l & 63;
        ef[f][d] = filt[(size_t)f * INNERc + h * 64 + d];
      }
      for (int l = tid; l < 64 * DHc; l += 256) {
        int cc = l >> 6, d = l & 63;
        wk[cc][d] = W[(size_t)(c0 + cc) * INNERc + h * 64 + d];
      }
      __syncthreads();
      int f = tid >> 3, cbase = tid & 7;
      float acc[8] = {};
#pragma unroll
      for (int d4 = 0; d4 < DHc; d4 += 4) {
        float4 a = *(const float4*)(&ef[f][d4]);
#pragma unroll
        for (int j = 0; j < 8; ++j) {
          float4 b = *(const float4*)(&wk[cbase + j * 8][d4]);
          acc[j] += a.x * b.x + a.y * b.y + a.z * b.z + a.w * b.w;
        }
      }
#pragma unroll
      for (int j = 0; j < 8; ++j)
        G[(size_t)(h * Fc + f) * Cc + c0 + cbase + j * 8] = f2bf(acc[j]);
    }
  }
}

// ---------------------------------------------------------------------------
// 2. Fused spatial attention chunk (V-projection fused; last-arriver does the
//    online-softmax reduction across the 18 chunks -> svT). No spinning.
// ---------------------------------------------------------------------------
__global__ __launch_bounds__(256) void spatial_kernel(
    const ushort* __restrict__ Gk, const ushort* __restrict__ ehsT,
    const ushort* __restrict__ WvT, const float* __restrict__ scale_p,
    float* __restrict__ svp, float* __restrict__ mj, float* __restrict__ lj,
    ushort* __restrict__ svT, int* __restrict__ cnt_sp) {
  int c = blockIdx.x, h = blockIdx.y, b = blockIdx.z;
  int tid = threadIdx.x, lane = tid & 63, wv = tid >> 6;
  int l15 = lane & 15, kq = lane >> 4;
  int pos0 = c * CHUNK_P;
  int bh = b * HEADSc + h;
  float s = scale_p[0];

  __shared__ alignas(16) ushort As[96 * 64];
  __shared__ alignas(16) ushort Bs[128 * 64];
  __shared__ float Sq[32 * 132];
  __shared__ alignas(16) ushort P[32 * 136];
  __shared__ alignas(16) ushort Vs[64 * 136];
  __shared__ int lastflag;

  const ushort* Av = WvT + (size_t)(h * 64) * Cc;
  const ushort* Ag = Gk + (size_t)(h * Fc) * Cc;
  const ushort* Bb = ehsT + ((size_t)b * Pc + pos0) * Cc;

  f32x4 acc[6][2] = {};
  for (int k0 = 0; k0 < Cc; k0 += 64) {
#pragma unroll
    for (int it = 0; it < 3; ++it) {
      int lin = it * 256 + tid;
      int row = lin >> 3, p = lin & 7;
      int lc = p ^ (row & 7);
      const ushort* sp = (row < 64) ? (Av + (size_t)row * Cc + k0 + lc * 8)
                                    : (Ag + (size_t)(row - 64) * Cc + k0 + lc * 8);
      *(uint4*)(&As[row * 64 + p * 8]) = *(const uint4*)sp;
    }
#pragma unroll
    for (int it = 0; it < 4; ++it) {
      int lin = it * 256 + tid;
      int row = lin >> 3, p = lin & 7;
      int lc = p ^ (row & 7);
      *(uint4*)(&Bs[row * 64 + p * 8]) =
          *(const uint4*)(Bb + (size_t)row * Cc + k0 + lc * 8);
    }
    __syncthreads();
#pragma unroll
    for (int ss = 0; ss < 2; ++ss) {
      bf16x8 af[6], bfr[2];
#pragma unroll
      for (int mt = 0; mt < 6; ++mt) {
        int m = mt * 16 + l15;
        int p = (ss * 4 + kq) ^ (m & 7);
        af[mt] = *(const bf16x8*)(&As[m * 64 + p * 8]);
      }
#pragma unroll
      for (int nt = 0; nt < 2; ++nt) {
        int n = wv * 32 + nt * 16 + l15;
        int p = (ss * 4 + kq) ^ (n & 7);
        bfr[nt] = *(const bf16x8*)(&Bs[n * 64 + p * 8]);
      }
#pragma unroll
      for (int mt = 0; mt < 6; ++mt)
#pragma unroll
        for (int nt = 0; nt < 2; ++nt)
          acc[mt][nt] = __builtin_amdgcn_mfma_f32_16x16x32_bf16(
              af[mt], bfr[nt], acc[mt][nt], 0, 0, 0);
    }
    __syncthreads();
  }
#pragma unroll
  for (int mt = 0; mt < 6; ++mt)
#pragma unroll
    for (int nt = 0; nt < 2; ++nt) {
      int col = wv * 32 + nt * 16 + l15;
#pragma unroll
      for (int r = 0; r < 4; ++r) {
        int row = mt * 16 + kq * 4 + r;
        if (mt < 4) Vs[row * 136 + col] = f2bf(acc[mt][nt][r]);
        else Sq[(row - 64) * 132 + col] = acc[mt][nt][r];
      }
    }
  __syncthreads();

  {
    int row = tid >> 3, sub = tid & 7;
    float vals[16];
    float m_ = -1e30f;
#pragma unroll
    for (int i = 0; i < 16; ++i) {
      vals[i] = s * Sq[row * 132 + sub * 16 + i];
      m_ = fmaxf(m_, vals[i]);
    }
    m_ = fmaxf(m_, __shfl_xor(m_, 1));
    m_ = fmaxf(m_, __shfl_xor(m_, 2));
    m_ = fmaxf(m_, __shfl_xor(m_, 4));
    float l_ = 0.f;
#pragma unroll
    for (int i = 0; i < 16; i += 2) {
      float e0 = __expf(vals[i] - m_);
      float e1 = __expf(vals[i + 1] - m_);
      l_ += e0 + e1;
      uint pk = (uint)f2bf(e0) | ((uint)f2bf(e1) << 16);
      *(uint*)(&P[row * 136 + sub * 16 + i]) = pk;
    }
    l_ += __shfl_xor(l_, 1);
    l_ += __shfl_xor(l_, 2);
    l_ += __shfl_xor(l_, 4);
    if (sub == 0) {
      mj[((size_t)c * 16 + bh) * Fc + row] = m_;
      lj[((size_t)c * 16 + bh) * Fc + row] = l_;
    }
  }
  __syncthreads();

  f32x4 acc2[2] = {};
#pragma unroll
  for (int ss = 0; ss < 4; ++ss) {
    bf16x8 af[2];
#pragma unroll
    for (int mt = 0; mt < 2; ++mt)
      af[mt] = *(const bf16x8*)(&P[(mt * 16 + l15) * 136 + ss * 32 + kq * 8]);
    bf16x8 bfr = *(const bf16x8*)(&Vs[(wv * 16 + l15) * 136 + ss * 32 + kq * 8]);
#pragma unroll
    for (int mt = 0; mt < 2; ++mt)
      acc2[mt] = __builtin_amdgcn_mfma_f32_16x16x32_bf16(af[mt], bfr, acc2[mt],
                                                         0, 0, 0);
  }
  float* op = svp + ((size_t)c * 16 + bh) * (Fc * DHc);
#pragma unroll
  for (int mt = 0; mt < 2; ++mt)
#pragma unroll
    for (int r = 0; r < 4; ++r)
      op[(mt * 16 + kq * 4 + r) * DHc + wv * 16 + l15] = acc2[mt][r];

  // ---- last-arriver reduction (device-scope release/acquire)
  __threadfence();
  if (tid == 0) {
    int old = __hip_atomic_fetch_add(&cnt_sp[bh], 1, __ATOMIC_ACQ_REL,
                                     __HIP_MEMORY_SCOPE_AGENT);
    lastflag = (old == CHUNKS - 1);
  }
  __syncthreads();
  if (!lastflag) return;
  __threadfence();  // acquire-side ordering for svp/mj/lj reads
  for (int l = tid; l < Fc * DHc; l += 256) {
    int d = l & 63, f = l >> 6;
    float m = -1e30f;
#pragma unroll
    for (int cc = 0; cc < CHUNKS; ++cc)
      m = fmaxf(m, mj[((size_t)cc * 16 + bh) * Fc + f]);
    float osum = 0.f, lsum = 0.f;
#pragma unroll
    for (int cc = 0; cc < CHUNKS; ++cc) {
      float w = __expf(mj[((size_t)cc * 16 + bh) * Fc + f] - m);
      osum += w * svp[((size_t)cc * 16 + bh) * (Fc * DHc) + f * DHc + d];
      lsum += w * lj[((size_t)cc * 16 + bh) * Fc + f];
    }
    svT[((size_t)bh * DHc + d) * Fc + f] = f2bf(osum / lsum);
  }
}

// ---------------------------------------------------------------------------
// 3. Merged channel attention + final GEMM (468 blocks, 1-D grid):
//    [0,288): channel -> OAT, release-increment cnt_cf[b*18 + pb/2]
//    [288,468): final GEMM; acquire-spin until its 8 producers arrived.
//    Union LDS 45KB -> 3 blocks/CU -> all 468 co-resident (no deadlock).
// ---------------------------------------------------------------------------
__global__ __launch_bounds__(256) void chanfinal_kernel(
    const ushort* __restrict__ Gq, const ushort* __restrict__ hsT,
    const ushort* __restrict__ svT, const float* __restrict__ scale_p,
    ushort* __restrict__ OAT, const ushort* __restrict__ WoT,
    const float* __restrict__ bo, const float* __restrict__ res,
    float* __restrict__ Out, int* __restrict__ cnt_cf) {
  __shared__ char smem[45056] __attribute__((aligned(16)));
  int idx = blockIdx.x, tid = threadIdx.x;
  int lane = tid & 63, wv = tid >> 6;
  int l15 = lane & 15, kq = lane >> 4;
  float s = scale_p[0];

  if (idx < 288) {
    // ================= channel attention =================
    int pb = idx % 36, hp = (idx / 36) % 4, b = idx / 144;
    int pos0 = pb * 64;
    ushort (*Aq)[32 * 64] = (ushort(*)[32 * 64])smem;            // 8192 B
    ushort* Bs = (ushort*)(smem + 8192);                         // 8192 B
    float* SO = (float*)(smem + 16384);                          // 17408 B
    ushort* Pt = (ushort*)(smem + 33792);                        // 5120 B
    ushort* svs = (ushort*)(smem + 38912);                       // 5120 B
    float* red = (float*)(smem + 44032);                         // 1024 B

    f32x4 acc[2][2] = {};
    const ushort* Bb = hsT + ((size_t)b * Pc + pos0) * Cc;
    for (int k0 = 0; k0 < Cc; k0 += 64) {
#pragma unroll
      for (int it = 0; it < 2; ++it) {
        int lin = it * 256 + tid;
        int hh = lin >> 8, row = (lin >> 3) & 31, p = lin & 7;
        int lc = p ^ (row & 7);
        *(uint4*)(&Aq[hh][row * 64 + p * 8]) = *(const uint4*)(
            Gq + (size_t)((hp * 2 + hh) * Fc + row) * Cc + k0 + lc * 8);
      }
#pragma unroll
      for (int it = 0; it < 2; ++it) {
        int lin = it * 256 + tid;
        int row = lin >> 3, p = lin & 7;
        int lc = p ^ (row & 7);
        *(uint4*)(&Bs[row * 64 + p * 8]) =
            *(const uint4*)(Bb + (size_t)row * Cc + k0 + lc * 8);
      }
      __syncthreads();
#pragma unroll
      for (int ss = 0; ss < 2; ++ss) {
        int n = wv * 16 + l15;
        int pb_ = (ss * 4 + kq) ^ (n & 7);
        bf16x8 bfr = *(const bf16x8*)(&Bs[n * 64 + pb_ * 8]);
#pragma unroll
        for (int hh = 0; hh < 2; ++hh)
#pragma unroll
          for (int mt = 0; mt < 2; ++mt) {
            int m = mt * 16 + l15;
            int pa = (ss * 4 + kq) ^ (m & 7);
            bf16x8 af = *(const bf16x8*)(&Aq[hh][m * 64 + pa * 8]);
            acc[hh][mt] = __builtin_amdgcn_mfma_f32_16x16x32_bf16(
                af, bfr, acc[hh][mt], 0, 0, 0);
          }
      }
      __syncthreads();
    }

    for (int hh = 0; hh < 2; ++hh) {
      int h = hp * 2 + hh;
#pragma unroll
      for (int mt = 0; mt < 2; ++mt)
#pragma unroll
        for (int r = 0; r < 4; ++r)
          SO[(mt * 16 + kq * 4 + r) * 68 + wv * 16 + l15] = acc[hh][mt][r];
      {
        int rr = tid >> 2, p = tid & 3;
        *(uint4*)(&svs[rr * 40 + p * 8]) = *(const uint4*)(
            svT + ((size_t)(b * HEADSc + h) * DHc + rr) * Fc + p * 8);
      }
      __syncthreads();
      {
        int pos = tid & 63, g = tid >> 6;
        float v8[8];
        float pm = -1e30f;
#pragma unroll
        for (int i = 0; i < 8; ++i) {
          v8[i] = s * SO[(g * 8 + i) * 68 + pos];
          pm = fmaxf(pm, v8[i]);
        }
        red[g * 64 + pos] = pm;
        __syncthreads();
        float m_ = fmaxf(fmaxf(red[pos], red[64 + pos]),
                         fmaxf(red[128 + pos], red[192 + pos]));
        __syncthreads();
        float ps = 0.f;
#pragma unroll
        for (int i = 0; i < 8; ++i) {
          v8[i] = __expf(v8[i] - m_);
          ps += v8[i];
        }
        red[g * 64 + pos] = ps;
        __syncthreads();
        float inv = 1.f / (red[pos] + red[64 + pos] + red[128 + pos] +
                           red[192 + pos]);
#pragma unroll
        for (int i = 0; i < 8; i += 2) {
          uint pk = (uint)f2bf(v8[i] * inv) |
                    ((uint)f2bf(v8[i + 1] * inv) << 16);
          *(uint*)(&Pt[pos * 40 + g * 8 + i]) = pk;
        }
      }
      __syncthreads();
      {
        bf16x8 b_ = *(const bf16x8*)(&svs[(wv * 16 + l15) * 40 + kq * 8]);
        f32x4 acc3[4];
#pragma unroll
        for (int mt = 0; mt < 4; ++mt) {
          bf16x8 a_ = *(const bf16x8*)(&Pt[(mt * 16 + l15) * 40 + kq * 8]);
          f32x4 z = {0.f, 0.f, 0.f, 0.f};
          acc3[mt] =
              __builtin_amdgcn_mfma_f32_16x16x32_bf16(a_, b_, z, 0, 0, 0);
        }
#pragma unroll
        for (int mt = 0; mt < 4; ++mt)
#pragma unroll
          for (int r = 0; r < 4; ++r)
            SO[(mt * 16 + kq * 4 + r) * 68 + wv * 16 + l15] = acc3[mt][r];
      }
      __syncthreads();
#pragma unroll
      for (int it = 0; it < 2; ++it) {
        int lin = it * 256 + tid;
        int p = lin >> 3, c8 = lin & 7;
        ushort tmp[8];
#pragma unroll
        for (int j = 0; j < 8; ++j) tmp[j] = f2bf(SO[p * 68 + c8 * 8 + j]);
        *(uint4*)(&OAT[((size_t)b * Pc + pos0 + p) * INNERc + h * 64 +
                       c8 * 8]) = *(const uint4*)tmp;
      }
      __syncthreads();
    }
    // release: OAT tile for (b, pos128 = pb/2) heads [hp*2, hp*2+1] done
    __threadfence();
    if (tid == 0)
      __hip_atomic_fetch_add(&cnt_cf[b * 18 + (pb >> 1)], 1, __ATOMIC_RELEASE,
                             __HIP_MEMORY_SCOPE_AGENT);
  } else {
    // ================= final GEMM =================
    int i = idx - 288;
    int x = i % 18, y = (i / 18) % 5, b = i / 90;
    int n0 = x * 128, m0 = y * 64;
    const int K = INNERc;
    ushort* As = (ushort*)smem;               // 8192 B
    ushort* Bs = (ushort*)(smem + 8192);      // 16384 B

    // acquire-spin: wait for the 8 channel producers of this pos128 tile
    if (tid == 0) {
      int iters = 0;
      while (__hip_atomic_load(&cnt_cf[b * 18 + x], __ATOMIC_ACQUIRE,
                               __HIP_MEMORY_SCOPE_AGENT) < 8 &&
             iters < 100000000) {
        __builtin_amdgcn_s_sleep(8);
        ++iters;
      }
    }
    __syncthreads();

    const ushort* Ab = WoT + (size_t)m0 * K;
    const ushort* Bb = OAT + ((size_t)b * Pc + n0) * K;
    f32x4 acc[4][2] = {};
    for (int k0 = 0; k0 < K; k0 += 64) {
#pragma unroll
      for (int it = 0; it < 2; ++it) {
        int lin = it * 256 + tid;
        int row = lin >> 3, p = lin & 7;
        int lc = p ^ (row & 7);
        *(uint4*)(&As[row * 64 + p * 8]) =
            *(const uint4*)(Ab + (size_t)row * K + k0 + lc * 8);
      }
#pragma unroll
      for (int it = 0; it < 4; ++it) {
        int lin = it * 256 + tid;
        int row = lin >> 3, p = lin & 7;
        int lc = p ^ (row & 7);
        *(uint4*)(&Bs[row * 64 + p * 8]) =
            *(const uint4*)(Bb + (size_t)row * K + k0 + lc * 8);
      }
      __syncthreads();
#pragma unroll
      for (int ss = 0; ss < 2; ++ss) {
        bf16x8 af[4], bfr[2];
#pragma unroll
        for (int mt = 0; mt < 4; ++mt) {
          int m = mt * 16 + l15;
          int p = (ss * 4 + kq) ^ (m & 7);
          af[mt] = *(const bf16x8*)(&As[m * 64 + p * 8]);
        }
#pragma unroll
        for (int nt = 0; nt < 2; ++nt) {
          int n = wv * 32 + nt * 16 + l15;
          int p = (ss * 4 + kq) ^ (n & 7);
          bfr[nt] = *(const bf16x8*)(&Bs[n * 64 + p * 8]);
        }
#pragma unroll
        for (int mt = 0; mt < 4; ++mt)
#pragma unroll
          for (int nt = 0; nt < 2; ++nt)
            acc[mt][nt] = __builtin_amdgcn_mfma_f32_16x16x32_bf16(
                af[mt], bfr[nt], acc[mt][nt], 0, 0, 0);
      }
      __syncthreads();
    }
    float* Ob = Out + ((size_t)b * Cc + m0) * Pc + n0;
    const float* rb = res + ((size_t)b * Cc + m0) * Pc + n0;
#pragma unroll
    for (int mt = 0; mt < 4; ++mt)
#pragma unroll
      for (int nt = 0; nt < 2; ++nt) {
        int ncol = wv * 32 + nt * 16 + l15;
#pragma unroll
        for (int r = 0; r < 4; ++r) {
          int m = mt * 16 + kq * 4 + r;
          Ob[(size_t)m * Pc + ncol] =
              acc[mt][nt][r] + bo[m0 + m] + s * rb[(size_t)m * Pc + ncol];
        }
      }
  }
}

// ---------------------------------------------------------------------------
extern "C" void kernel_launch(void* const* d_in, const int* in_sizes, int n_in,
                              void* d_out, int out_size, void* d_ws, size_t ws_size,
                              hipStream_t stream) {
  const float* hs    = (const float*)d_in[0];
  const float* ehs   = (const float*)d_in[1];
  const float* Wq    = (const float*)d_in[2];
  const float* Wk    = (const float*)d_in[3];
  const float* Wv    = (const float*)d_in[4];
  const float* Wo    = (const float*)d_in[5];
  const float* bo    = (const float*)d_in[6];
  const float* gamma = (const float*)d_in[7];
  const float* beta  = (const float*)d_in[8];
  const float* exf   = (const float*)d_in[9];
  const float* dif   = (const float*)d_in[10];
  const float* scale = (const float*)d_in[11];
  float* out = (float*)d_out;

  float* ws = (float*)d_ws;
  float* svp = ws;                         //   589,824 f
  float* mj  = svp + 589824;               //     9,216 f
  float* lj  = mj + 9216;                  //     9,216 f
  int* counters = (int*)(lj + 9216);       //        64 i (16 spatial + 36 cf)
  ushort* hsT  = (ushort*)(counters + 64); // 1,474,560 us
  ushort* ehsT = hsT + 1474560;            // 1,474,560 us
  ushort* WvT  = ehsT + 1474560;           //   163,840 us
  ushort* WoT  = WvT + 163840;             //   163,840 us
  ushort* Gk   = WoT + 163840;             //    81,920 us
  ushort* Gq   = Gk + 81920;               //    81,920 us
  ushort* svT  = Gq + 81920;               //    32,768 us
  ushort* OAT  = svT + 32768;              // 2,359,296 us
  int* cnt_sp = counters;                  // [16]
  int* cnt_cf = counters + 16;             // [36]

  prep_all_kernel<<<dim3(305), dim3(256), 0, stream>>>(
      hs, ehs, gamma, beta, Wv, Wo, exf, Wk, dif, Wq,
      hsT, ehsT, WvT, WoT, Gk, Gq, counters);
  spatial_kernel<<<dim3(CHUNKS, HEADSc, Bc), dim3(256), 0, stream>>>(
      Gk, ehsT, WvT, scale, svp, mj, lj, svT, cnt_sp);
  chanfinal_kernel<<<dim3(288 + 180), dim3(256), 0, stream>>>(
      Gq, hsT, svT, scale, OAT, WoT, bo, hs, out, cnt_cf);
}

// Round 9
// 176.242 us; speedup vs baseline: 1.2546x; 1.2546x over previous
//
#include <hip/hip_runtime.h>
#include <math.h>

#define Bc 2
#define Cc 320
#define Pc 2304
#define HEADSc 8
#define DHc 64
#define INNERc 512
#define Fc 32
#define LN_EPS 1e-5f
#define CHUNKS 18
#define CHUNK_P 128

typedef __attribute__((ext_vector_type(8))) short bf16x8;
typedef __attribute__((ext_vector_type(4))) float f32x4;

static __device__ __forceinline__ ushort f2bf(float x) {
  uint u = __builtin_bit_cast(uint, x);
  u = (u + 0x7fffu + ((u >> 16) & 1u)) >> 16;
  return (ushort)u;
}

// ---------------------------------------------------------------------------
// Transpose+cast tile helper: src fp32 [R][C] -> dst bf16 [C][R]; 64x64
// ---------------------------------------------------------------------------
static __device__ void transpose_tile(const float* __restrict__ src,
                                      ushort* __restrict__ dst, int R, int C,
                                      int r0, int c0, int tid,
                                      float (*t)[65]) {
#pragma unroll
  for (int it = 0; it < 4; ++it) {
    int lin = it * 256 + tid;
    int rr = lin >> 4, c4 = lin & 15;
    float4 v = *(const float4*)(&src[(size_t)(r0 + rr) * C + c0 + c4 * 4]);
    t[rr][c4 * 4 + 0] = v.x; t[rr][c4 * 4 + 1] = v.y;
    t[rr][c4 * 4 + 2] = v.z; t[rr][c4 * 4 + 3] = v.w;
  }
  __syncthreads();
#pragma unroll
  for (int it = 0; it < 2; ++it) {
    int lin = it * 256 + tid;
    int cc = lin >> 3, r8 = lin & 7;
    ushort tmp[8];
#pragma unroll
    for (int j = 0; j < 8; ++j) tmp[j] = f2bf(t[r8 * 8 + j][cc]);
    *(uint4*)(&dst[(size_t)(c0 + cc) * R + r0 + r8 * 8]) = *(const uint4*)tmp;
  }
}

// ---------------------------------------------------------------------------
// 1. ALL prep in one launch (305 blocks):
//    [0,144): activation transpose+cast (LN fused for ehs)
//    [144,184): WvT  [184,224): WoT  [224,304): gfuse Gk/Gq
//    304: zero the spatial arrival counters
// ---------------------------------------------------------------------------
__global__ __launch_bounds__(256) void prep_all_kernel(
    const float* __restrict__ hs, const float* __restrict__ ehs,
    const float* __restrict__ gamma, const float* __restrict__ beta,
    const float* __restrict__ Wv, const float* __restrict__ Wo,
    const float* __restrict__ exf, const float* __restrict__ Wk,
    const float* __restrict__ dif, const float* __restrict__ Wq,
    ushort* __restrict__ hsT, ushort* __restrict__ ehsT,
    ushort* __restrict__ WvT, ushort* __restrict__ WoT,
    ushort* __restrict__ Gk, ushort* __restrict__ Gq,
    int* __restrict__ counters) {
  __shared__ float smem[6448];
  int idx = blockIdx.x, tid = threadIdx.x;

  if (idx == 304) {
    if (tid < 64) counters[tid] = 0;
    return;
  }
  if (idx < 144) {
    int pt = idx % 36, z = idx / 36;
    int b = z & 1, which = z >> 1;
    int pos0 = pt * 64;
    const float* src = (which ? ehs : hs) + (size_t)b * Cc * Pc;
    ushort* dst = (which ? ehsT : hsT) + (size_t)b * Pc * Cc;
    float* t = smem;               // [64][65]
    float* s1 = smem + 4160;
    float* s2 = smem + 4416;
    float* lmean = smem + 4672;
    float* lrstd = smem + 4736;
    int lane = tid & 63, g = tid >> 6;
    if (which) {
      const float* base = src + pos0 + lane;
      float sum = 0.f, sq = 0.f;
      for (int c = g * 80; c < g * 80 + 80; ++c) {
        float x = base[(size_t)c * Pc];
        sum += x; sq += x * x;
      }
      s1[g * 64 + lane] = sum; s2[g * 64 + lane] = sq;
      __syncthreads();
      if (tid < 64) {
        float ts = s1[tid] + s1[64 + tid] + s1[128 + tid] + s1[192 + tid];
        float tq = s2[tid] + s2[64 + tid] + s2[128 + tid] + s2[192 + tid];
        float mean = ts / (float)Cc;
        float var = tq / (float)Cc - mean * mean;
        lmean[tid] = mean;
        lrstd[tid] = rsqrtf(var + LN_EPS);
      }
      __syncthreads();
    }
    for (int ct = 0; ct < 5; ++ct) {
      int r0 = ct * 64;
#pragma unroll
      for (int it = 0; it < 4; ++it) {
        int lin = it * 256 + tid;
        int rr = lin >> 4, c4 = lin & 15;
        float4 v = *(const float4*)(&src[(size_t)(r0 + rr) * Pc + pos0 + c4 * 4]);
        t[rr * 65 + c4 * 4 + 0] = v.x; t[rr * 65 + c4 * 4 + 1] = v.y;
        t[rr * 65 + c4 * 4 + 2] = v.z; t[rr * 65 + c4 * 4 + 3] = v.w;
      }
      __syncthreads();
#pragma unroll
      for (int it = 0; it < 2; ++it) {
        int lin = it * 256 + tid;
        int cc = lin >> 3, r8 = lin & 7;
        float m_ = which ? lmean[cc] : 0.f, rs_ = which ? lrstd[cc] : 1.f;
        ushort tmp[8];
#pragma unroll
        for (int j = 0; j < 8; ++j) {
          int ch = r8 * 8 + j;
          float x = t[ch * 65 + cc];
          float val = which ? (x - m_) * rs_ * gamma[r0 + ch] + beta[r0 + ch] : x;
          tmp[j] = f2bf(val);
        }
        *(uint4*)(&dst[(size_t)(pos0 + cc) * Cc + r0 + r8 * 8]) =
            *(const uint4*)tmp;
      }
      __syncthreads();
    }
  } else {
    int idx2 = idx - 144;
    if (idx2 < 40) {
      transpose_tile(Wv, WvT, Cc, INNERc, (idx2 / 8) * 64, (idx2 % 8) * 64,
                     tid, (float(*)[65])smem);
    } else if (idx2 < 80) {
      int i = idx2 - 40;
      transpose_tile(Wo, WoT, INNERc, Cc, (i / 5) * 64, (i % 5) * 64, tid,
                     (float(*)[65])smem);
    } else {
      int i = idx2 - 80;
      int c0 = (i % 5) * 64, h = (i / 5) % 8, zz = i / 40;
      const float* filt = zz ? dif : exf;
      const float* W = zz ? Wq : Wk;
      ushort* G = zz ? Gq : Gk;
      float (*ef)[66] = (float(*)[66])smem;
      float (*wk)[65] = (float(*)[65])(smem + 32 * 66);
      for (int l = tid; l < Fc * DHc; l += 256) {
        int f = l >> 6, d = l & 63;
        ef[f][d] = filt[(size_t)f * INNERc + h * 64 + d];
      }
      for (int l = tid; l < 64 * DHc; l += 256) {
        int cc = l >> 6, d = l & 63;
        wk[cc][d] = W[(size_t)(c0 + cc) * INNERc + h * 64 + d];
      }
      __syncthreads();
      int f = tid >> 3, cbase = tid & 7;
      float acc[8] = {};
#pragma unroll
      for (int d4 = 0; d4 < DHc; d4 += 4) {
        float4 a = *(const float4*)(&ef[f][d4]);
#pragma unroll
        for (int j = 0; j < 8; ++j) {
          float4 b = *(const float4*)(&wk[cbase + j * 8][d4]);
          acc[j] += a.x * b.x + a.y * b.y + a.z * b.z + a.w * b.w;
        }
      }
#pragma unroll
      for (int j = 0; j < 8; ++j)
        G[(size_t)(h * Fc + f) * Cc + c0 + cbase + j * 8] = f2bf(acc[j]);
    }
  }
}

// ---------------------------------------------------------------------------
// 2. Fused spatial attention chunk (V-projection fused; last-arriver does the
//    online-softmax reduction across the 18 chunks -> svT). No spinning.
// ---------------------------------------------------------------------------
__global__ __launch_bounds__(256) void spatial_kernel(
    const ushort* __restrict__ Gk, const ushort* __restrict__ ehsT,
    const ushort* __restrict__ WvT, const float* __restrict__ scale_p,
    float* __restrict__ svp, float* __restrict__ mj, float* __restrict__ lj,
    ushort* __restrict__ svT, int* __restrict__ cnt_sp) {
  int c = blockIdx.x, h = blockIdx.y, b = blockIdx.z;
  int tid = threadIdx.x, lane = tid & 63, wv = tid >> 6;
  int l15 = lane & 15, kq = lane >> 4;
  int pos0 = c * CHUNK_P;
  int bh = b * HEADSc + h;
  float s = scale_p[0];

  __shared__ alignas(16) ushort As[96 * 64];
  __shared__ alignas(16) ushort Bs[128 * 64];
  __shared__ float Sq[32 * 132];
  __shared__ alignas(16) ushort P[32 * 136];
  __shared__ alignas(16) ushort Vs[64 * 136];
  __shared__ int lastflag;

  const ushort* Av = WvT + (size_t)(h * 64) * Cc;
  const ushort* Ag = Gk + (size_t)(h * Fc) * Cc;
  const ushort* Bb = ehsT + ((size_t)b * Pc + pos0) * Cc;

  f32x4 acc[6][2] = {};
  for (int k0 = 0; k0 < Cc; k0 += 64) {
#pragma unroll
    for (int it = 0; it < 3; ++it) {
      int lin = it * 256 + tid;
      int row = lin >> 3, p = lin & 7;
      int lc = p ^ (row & 7);
      const ushort* sp = (row < 64) ? (Av + (size_t)row * Cc + k0 + lc * 8)
                                    : (Ag + (size_t)(row - 64) * Cc + k0 + lc * 8);
      *(uint4*)(&As[row * 64 + p * 8]) = *(const uint4*)sp;
    }
#pragma unroll
    for (int it = 0; it < 4; ++it) {
      int lin = it * 256 + tid;
      int row = lin >> 3, p = lin & 7;
      int lc = p ^ (row & 7);
      *(uint4*)(&Bs[row * 64 + p * 8]) =
          *(const uint4*)(Bb + (size_t)row * Cc + k0 + lc * 8);
    }
    __syncthreads();
#pragma unroll
    for (int ss = 0; ss < 2; ++ss) {
      bf16x8 af[6], bfr[2];
#pragma unroll
      for (int mt = 0; mt < 6; ++mt) {
        int m = mt * 16 + l15;
        int p = (ss * 4 + kq) ^ (m & 7);
        af[mt] = *(const bf16x8*)(&As[m * 64 + p * 8]);
      }
#pragma unroll
      for (int nt = 0; nt < 2; ++nt) {
        int n = wv * 32 + nt * 16 + l15;
        int p = (ss * 4 + kq) ^ (n & 7);
        bfr[nt] = *(const bf16x8*)(&Bs[n * 64 + p * 8]);
      }
#pragma unroll
      for (int mt = 0; mt < 6; ++mt)
#pragma unroll
        for (int nt = 0; nt < 2; ++nt)
          acc[mt][nt] = __builtin_amdgcn_mfma_f32_16x16x32_bf16(
              af[mt], bfr[nt], acc[mt][nt], 0, 0, 0);
    }
    __syncthreads();
  }
#pragma unroll
  for (int mt = 0; mt < 6; ++mt)
#pragma unroll
    for (int nt = 0; nt < 2; ++nt) {
      int col = wv * 32 + nt * 16 + l15;
#pragma unroll
      for (int r = 0; r < 4; ++r) {
        int row = mt * 16 + kq * 4 + r;
        if (mt < 4) Vs[row * 136 + col] = f2bf(acc[mt][nt][r]);
        else Sq[(row - 64) * 132 + col] = acc[mt][nt][r];
      }
    }
  __syncthreads();

  {
    int row = tid >> 3, sub = tid & 7;
    float vals[16];
    float m_ = -1e30f;
#pragma unroll
    for (int i = 0; i < 16; ++i) {
      vals[i] = s * Sq[row * 132 + sub * 16 + i];
      m_ = fmaxf(m_, vals[i]);
    }
    m_ = fmaxf(m_, __shfl_xor(m_, 1));
    m_ = fmaxf(m_, __shfl_xor(m_, 2));
    m_ = fmaxf(m_, __shfl_xor(m_, 4));
    float l_ = 0.f;
#pragma unroll
    for (int i = 0; i < 16; i += 2) {
      float e0 = __expf(vals[i] - m_);
      float e1 = __expf(vals[i + 1] - m_);
      l_ += e0 + e1;
      uint pk = (uint)f2bf(e0) | ((uint)f2bf(e1) << 16);
      *(uint*)(&P[row * 136 + sub * 16 + i]) = pk;
    }
    l_ += __shfl_xor(l_, 1);
    l_ += __shfl_xor(l_, 2);
    l_ += __shfl_xor(l_, 4);
    if (sub == 0) {
      mj[((size_t)c * 16 + bh) * Fc + row] = m_;
      lj[((size_t)c * 16 + bh) * Fc + row] = l_;
    }
  }
  __syncthreads();

  f32x4 acc2[2] = {};
#pragma unroll
  for (int ss = 0; ss < 4; ++ss) {
    bf16x8 af[2];
#pragma unroll
    for (int mt = 0; mt < 2; ++mt)
      af[mt] = *(const bf16x8*)(&P[(mt * 16 + l15) * 136 + ss * 32 + kq * 8]);
    bf16x8 bfr = *(const bf16x8*)(&Vs[(wv * 16 + l15) * 136 + ss * 32 + kq * 8]);
#pragma unroll
    for (int mt = 0; mt < 2; ++mt)
      acc2[mt] = __builtin_amdgcn_mfma_f32_16x16x32_bf16(af[mt], bfr, acc2[mt],
                                                         0, 0, 0);
  }
  float* op = svp + ((size_t)c * 16 + bh) * (Fc * DHc);
#pragma unroll
  for (int mt = 0; mt < 2; ++mt)
#pragma unroll
    for (int r = 0; r < 4; ++r)
      op[(mt * 16 + kq * 4 + r) * DHc + wv * 16 + l15] = acc2[mt][r];

  // ---- last-arriver reduction (single atomic per block; no spinning)
  __threadfence();
  if (tid == 0) {
    int old = __hip_atomic_fetch_add(&cnt_sp[bh], 1, __ATOMIC_ACQ_REL,
                                     __HIP_MEMORY_SCOPE_AGENT);
    lastflag = (old == CHUNKS - 1);
  }
  __syncthreads();
  if (!lastflag) return;
  __threadfence();
  for (int l = tid; l < Fc * DHc; l += 256) {
    int d = l & 63, f = l >> 6;
    float m = -1e30f;
#pragma unroll
    for (int cc = 0; cc < CHUNKS; ++cc)
      m = fmaxf(m, mj[((size_t)cc * 16 + bh) * Fc + f]);
    float osum = 0.f, lsum = 0.f;
#pragma unroll
    for (int cc = 0; cc < CHUNKS; ++cc) {
      float w = __expf(mj[((size_t)cc * 16 + bh) * Fc + f] - m);
      osum += w * svp[((size_t)cc * 16 + bh) * (Fc * DHc) + f * DHc + d];
      lsum += w * lj[((size_t)cc * 16 + bh) * Fc + f];
    }
    svT[((size_t)bh * DHc + d) * Fc + f] = f2bf(osum / lsum);
  }
}

// ---------------------------------------------------------------------------
// 3. Fused channel attention -> OAT[b][pos][h*64+d] bf16
// ---------------------------------------------------------------------------
__global__ __launch_bounds__(256) void channel_kernel(
    const ushort* __restrict__ Gq, const ushort* __restrict__ hsT,
    const ushort* __restrict__ svT, const float* __restrict__ scale_p,
    ushort* __restrict__ OAT) {
  int pb = blockIdx.x, hp = blockIdx.y, b = blockIdx.z;
  int pos0 = pb * 64;
  int tid = threadIdx.x, lane = tid & 63, wv = tid >> 6;
  int l15 = lane & 15, kq = lane >> 4;
  float s = scale_p[0];

  __shared__ alignas(16) ushort Aq[2][32 * 64];
  __shared__ alignas(16) ushort Bs[64 * 64];
  __shared__ float SO[64 * 68];
  __shared__ alignas(16) ushort Pt[64 * 40];
  __shared__ alignas(16) ushort svs[64 * 40];
  __shared__ float red[4 * 64];

  f32x4 acc[2][2] = {};
  const ushort* Bb = hsT + ((size_t)b * Pc + pos0) * Cc;
  for (int k0 = 0; k0 < Cc; k0 += 64) {
#pragma unroll
    for (int it = 0; it < 2; ++it) {
      int lin = it * 256 + tid;
      int hh = lin >> 8, row = (lin >> 3) & 31, p = lin & 7;
      int lc = p ^ (row & 7);
      *(uint4*)(&Aq[hh][row * 64 + p * 8]) = *(const uint4*)(
          Gq + (size_t)((hp * 2 + hh) * Fc + row) * Cc + k0 + lc * 8);
    }
#pragma unroll
    for (int it = 0; it < 2; ++it) {
      int lin = it * 256 + tid;
      int row = lin >> 3, p = lin & 7;
      int lc = p ^ (row & 7);
      *(uint4*)(&Bs[row * 64 + p * 8]) =
          *(const uint4*)(Bb + (size_t)row * Cc + k0 + lc * 8);
    }
    __syncthreads();
#pragma unroll
    for (int ss = 0; ss < 2; ++ss) {
      int n = wv * 16 + l15;
      int pb_ = (ss * 4 + kq) ^ (n & 7);
      bf16x8 bfr = *(const bf16x8*)(&Bs[n * 64 + pb_ * 8]);
#pragma unroll
      for (int hh = 0; hh < 2; ++hh)
#pragma unroll
        for (int mt = 0; mt < 2; ++mt) {
          int m = mt * 16 + l15;
          int pa = (ss * 4 + kq) ^ (m & 7);
          bf16x8 af = *(const bf16x8*)(&Aq[hh][m * 64 + pa * 8]);
          acc[hh][mt] = __builtin_amdgcn_mfma_f32_16x16x32_bf16(
              af, bfr, acc[hh][mt], 0, 0, 0);
        }
    }
    __syncthreads();
  }

  for (int hh = 0; hh < 2; ++hh) {
    int h = hp * 2 + hh;
#pragma unroll
    for (int mt = 0; mt < 2; ++mt)
#pragma unroll
      for (int r = 0; r < 4; ++r)
        SO[(mt * 16 + kq * 4 + r) * 68 + wv * 16 + l15] = acc[hh][mt][r];
    {
      int rr = tid >> 2, p = tid & 3;
      *(uint4*)(&svs[rr * 40 + p * 8]) = *(const uint4*)(
          svT + ((size_t)(b * HEADSc + h) * DHc + rr) * Fc + p * 8);
    }
    __syncthreads();
    {
      int pos = tid & 63, g = tid >> 6;
      float v8[8];
      float pm = -1e30f;
#pragma unroll
      for (int i = 0; i < 8; ++i) {
        v8[i] = s * SO[(g * 8 + i) * 68 + pos];
        pm = fmaxf(pm, v8[i]);
      }
      red[g * 64 + pos] = pm;
      __syncthreads();
      float m_ = fmaxf(fmaxf(red[pos], red[64 + pos]),
                       fmaxf(red[128 + pos], red[192 + pos]));
      __syncthreads();
      float ps = 0.f;
#pragma unroll
      for (int i = 0; i < 8; ++i) {
        v8[i] = __expf(v8[i] - m_);
        ps += v8[i];
      }
      red[g * 64 + pos] = ps;
      __syncthreads();
      float inv = 1.f / (red[pos] + red[64 + pos] + red[128 + pos] +
                         red[192 + pos]);
#pragma unroll
      for (int i = 0; i < 8; i += 2) {
        uint pk = (uint)f2bf(v8[i] * inv) | ((uint)f2bf(v8[i + 1] * inv) << 16);
        *(uint*)(&Pt[pos * 40 + g * 8 + i]) = pk;
      }
    }
    __syncthreads();
    {
      bf16x8 b_ = *(const bf16x8*)(&svs[(wv * 16 + l15) * 40 + kq * 8]);
      f32x4 acc3[4];
#pragma unroll
      for (int mt = 0; mt < 4; ++mt) {
        bf16x8 a_ = *(const bf16x8*)(&Pt[(mt * 16 + l15) * 40 + kq * 8]);
        f32x4 z = {0.f, 0.f, 0.f, 0.f};
        acc3[mt] = __builtin_amdgcn_mfma_f32_16x16x32_bf16(a_, b_, z, 0, 0, 0);
      }
#pragma unroll
      for (int mt = 0; mt < 4; ++mt)
#pragma unroll
        for (int r = 0; r < 4; ++r)
          SO[(mt * 16 + kq * 4 + r) * 68 + wv * 16 + l15] = acc3[mt][r];
    }
    __syncthreads();
#pragma unroll
    for (int it = 0; it < 2; ++it) {
      int lin = it * 256 + tid;
      int p = lin >> 3, c8 = lin & 7;
      ushort tmp[8];
#pragma unroll
      for (int j = 0; j < 8; ++j) tmp[j] = f2bf(SO[p * 68 + c8 * 8 + j]);
      *(uint4*)(&OAT[((size_t)b * Pc + pos0 + p) * INNERc + h * 64 + c8 * 8]) =
          *(const uint4*)tmp;
    }
    __syncthreads();
  }
}

// ---------------------------------------------------------------------------
// 4. Final GEMM: out = WoT . OAT + bias + s*res. K=512.
// ---------------------------------------------------------------------------
__global__ __launch_bounds__(256) void gemm_mfma_kernel(
    const ushort* __restrict__ A, const ushort* __restrict__ Bt,
    float* __restrict__ Out, int K, int Mdim,
    const float* __restrict__ bias, const float* __restrict__ res,
    const float* __restrict__ scale_p) {
  int b = blockIdx.z;
  int n0 = blockIdx.x * 128, m0 = blockIdx.y * 64;
  int tid = threadIdx.x, lane = tid & 63, wv = tid >> 6;
  int l15 = lane & 15, kq = lane >> 4;
  __shared__ alignas(16) ushort As[64 * 64];
  __shared__ alignas(16) ushort Bs[128 * 64];
  const ushort* Ab = A + (size_t)m0 * K;
  const ushort* Bb = Bt + ((size_t)b * Pc + n0) * K;

  f32x4 acc[4][2] = {};
  for (int k0 = 0; k0 < K; k0 += 64) {
#pragma unroll
    for (int it = 0; it < 2; ++it) {
      int lin = it * 256 + tid;
      int row = lin >> 3, p = lin & 7;
      int lc = p ^ (row & 7);
      *(uint4*)(&As[row * 64 + p * 8]) =
          *(const uint4*)(Ab + (size_t)row * K + k0 + lc * 8);
    }
#pragma unroll
    for (int it = 0; it < 4; ++it) {
      int lin = it * 256 + tid;
      int row = lin >> 3, p = lin & 7;
      int lc = p ^ (row & 7);
      *(uint4*)(&Bs[row * 64 + p * 8]) =
          *(const uint4*)(Bb + (size_t)row * K + k0 + lc * 8);
    }
    __syncthreads();
#pragma unroll
    for (int ss = 0; ss < 2; ++ss) {
      bf16x8 af[4], bfr[2];
#pragma unroll
      for (int mt = 0; mt < 4; ++mt) {
        int m = mt * 16 + l15;
        int p = (ss * 4 + kq) ^ (m & 7);
        af[mt] = *(const bf16x8*)(&As[m * 64 + p * 8]);
      }
#pragma unroll
      for (int nt = 0; nt < 2; ++nt) {
        int n = wv * 32 + nt * 16 + l15;
        int p = (ss * 4 + kq) ^ (n & 7);
        bfr[nt] = *(const bf16x8*)(&Bs[n * 64 + p * 8]);
      }
#pragma unroll
      for (int mt = 0; mt < 4; ++mt)
#pragma unroll
        for (int nt = 0; nt < 2; ++nt)
          acc[mt][nt] = __builtin_amdgcn_mfma_f32_16x16x32_bf16(
              af[mt], bfr[nt], acc[mt][nt], 0, 0, 0);
    }
    __syncthreads();
  }
  float s = scale_p[0];
  float* Ob = Out + ((size_t)b * Mdim + m0) * Pc + n0;
  const float* rb = res + ((size_t)b * Mdim + m0) * Pc + n0;
#pragma unroll
  for (int mt = 0; mt < 4; ++mt)
#pragma unroll
    for (int nt = 0; nt < 2; ++nt) {
      int ncol = wv * 32 + nt * 16 + l15;
#pragma unroll
      for (int r = 0; r < 4; ++r) {
        int m = mt * 16 + kq * 4 + r;
        Ob[(size_t)m * Pc + ncol] =
            acc[mt][nt][r] + bias[m0 + m] + s * rb[(size_t)m * Pc + ncol];
      }
    }
}

// ---------------------------------------------------------------------------
extern "C" void kernel_launch(void* const* d_in, const int* in_sizes, int n_in,
                              void* d_out, int out_size, void* d_ws, size_t ws_size,
                              hipStream_t stream) {
  const float* hs    = (const float*)d_in[0];
  const float* ehs   = (const float*)d_in[1];
  const float* Wq    = (const float*)d_in[2];
  const float* Wk    = (const float*)d_in[3];
  const float* Wv    = (const float*)d_in[4];
  const float* Wo    = (const float*)d_in[5];
  const float* bo    = (const float*)d_in[6];
  const float* gamma = (const float*)d_in[7];
  const float* beta  = (const float*)d_in[8];
  const float* exf   = (const float*)d_in[9];
  const float* dif   = (const float*)d_in[10];
  const float* scale = (const float*)d_in[11];
  float* out = (float*)d_out;

  float* ws = (float*)d_ws;
  float* svp = ws;                         //   589,824 f
  float* mj  = svp + 589824;               //     9,216 f
  float* lj  = mj + 9216;                  //     9,216 f
  int* counters = (int*)(lj + 9216);       //        64 i
  ushort* hsT  = (ushort*)(counters + 64); // 1,474,560 us
  ushort* ehsT = hsT + 1474560;            // 1,474,560 us
  ushort* WvT  = ehsT + 1474560;           //   163,840 us
  ushort* WoT  = WvT + 163840;             //   163,840 us
  ushort* Gk   = WoT + 163840;             //    81,920 us
  ushort* Gq   = Gk + 81920;               //    81,920 us
  ushort* svT  = Gq + 81920;               //    32,768 us
  ushort* OAT  = svT + 32768;              // 2,359,296 us
  int* cnt_sp = counters;                  // [16]

  prep_all_kernel<<<dim3(305), dim3(256), 0, stream>>>(
      hs, ehs, gamma, beta, Wv, Wo, exf, Wk, dif, Wq,
      hsT, ehsT, WvT, WoT, Gk, Gq, counters);
  spatial_kernel<<<dim3(CHUNKS, HEADSc, Bc), dim3(256), 0, stream>>>(
      Gk, ehsT, WvT, scale, svp, mj, lj, svT, cnt_sp);
  channel_kernel<<<dim3(Pc / 64, HEADSc / 2, Bc), dim3(256), 0, stream>>>(
      Gq, hsT, svT, scale, OAT);
  gemm_mfma_kernel<<<dim3(Pc / 128, Cc / 64, Bc), dim3(256), 0, stream>>>(
      WoT, OAT, out, INNERc, Cc, bo, hs, scale);
}

// Round 10
// 141.634 us; speedup vs baseline: 1.5612x; 1.2443x over previous
//
#include <hip/hip_runtime.h>
#include <math.h>

#define Bc 2
#define Cc 320
#define Pc 2304
#define HEADSc 8
#define DHc 64
#define INNERc 512
#define Fc 32
#define LN_EPS 1e-5f
#define CHUNKS 18
#define CHUNK_P 128

typedef __attribute__((ext_vector_type(8))) short bf16x8;
typedef __attribute__((ext_vector_type(4))) float f32x4;

static __device__ __forceinline__ ushort f2bf(float x) {
  uint u = __builtin_bit_cast(uint, x);
  u = (u + 0x7fffu + ((u >> 16) & 1u)) >> 16;
  return (ushort)u;
}

// ---------------------------------------------------------------------------
// Transpose+cast tile helper: src fp32 [R][C] -> dst bf16 [C][R]; 64x64
// ---------------------------------------------------------------------------
static __device__ void transpose_tile(const float* __restrict__ src,
                                      ushort* __restrict__ dst, int R, int C,
                                      int r0, int c0, int tid,
                                      float (*t)[65]) {
#pragma unroll
  for (int it = 0; it < 4; ++it) {
    int lin = it * 256 + tid;
    int rr = lin >> 4, c4 = lin & 15;
    float4 v = *(const float4*)(&src[(size_t)(r0 + rr) * C + c0 + c4 * 4]);
    t[rr][c4 * 4 + 0] = v.x; t[rr][c4 * 4 + 1] = v.y;
    t[rr][c4 * 4 + 2] = v.z; t[rr][c4 * 4 + 3] = v.w;
  }
  __syncthreads();
#pragma unroll
  for (int it = 0; it < 2; ++it) {
    int lin = it * 256 + tid;
    int cc = lin >> 3, r8 = lin & 7;
    ushort tmp[8];
#pragma unroll
    for (int j = 0; j < 8; ++j) tmp[j] = f2bf(t[r8 * 8 + j][cc]);
    *(uint4*)(&dst[(size_t)(c0 + cc) * R + r0 + r8 * 8]) = *(const uint4*)tmp;
  }
}

// ---------------------------------------------------------------------------
// 1. ALL prep in one launch (304 blocks):
//    [0,144): activation transpose+cast (LN fused for ehs)
//    [144,184): WvT  [184,224): WoT  [224,304): gfuse Gk/Gq
// ---------------------------------------------------------------------------
__global__ __launch_bounds__(256) void prep_all_kernel(
    const float* __restrict__ hs, const float* __restrict__ ehs,
    const float* __restrict__ gamma, const float* __restrict__ beta,
    const float* __restrict__ Wv, const float* __restrict__ Wo,
    const float* __restrict__ exf, const float* __restrict__ Wk,
    const float* __restrict__ dif, const float* __restrict__ Wq,
    ushort* __restrict__ hsT, ushort* __restrict__ ehsT,
    ushort* __restrict__ WvT, ushort* __restrict__ WoT,
    ushort* __restrict__ Gk, ushort* __restrict__ Gq) {
  __shared__ float smem[6448];
  int idx = blockIdx.x, tid = threadIdx.x;

  if (idx < 144) {
    int pt = idx % 36, z = idx / 36;
    int b = z & 1, which = z >> 1;
    int pos0 = pt * 64;
    const float* src = (which ? ehs : hs) + (size_t)b * Cc * Pc;
    ushort* dst = (which ? ehsT : hsT) + (size_t)b * Pc * Cc;
    float* t = smem;               // [64][65]
    float* s1 = smem + 4160;
    float* s2 = smem + 4416;
    float* lmean = smem + 4672;
    float* lrstd = smem + 4736;
    int lane = tid & 63, g = tid >> 6;
    if (which) {
      const float* base = src + pos0 + lane;
      float sum = 0.f, sq = 0.f;
      for (int c = g * 80; c < g * 80 + 80; ++c) {
        float x = base[(size_t)c * Pc];
        sum += x; sq += x * x;
      }
      s1[g * 64 + lane] = sum; s2[g * 64 + lane] = sq;
      __syncthreads();
      if (tid < 64) {
        float ts = s1[tid] + s1[64 + tid] + s1[128 + tid] + s1[192 + tid];
        float tq = s2[tid] + s2[64 + tid] + s2[128 + tid] + s2[192 + tid];
        float mean = ts / (float)Cc;
        float var = tq / (float)Cc - mean * mean;
        lmean[tid] = mean;
        lrstd[tid] = rsqrtf(var + LN_EPS);
      }
      __syncthreads();
    }
    for (int ct = 0; ct < 5; ++ct) {
      int r0 = ct * 64;
#pragma unroll
      for (int it = 0; it < 4; ++it) {
        int lin = it * 256 + tid;
        int rr = lin >> 4, c4 = lin & 15;
        float4 v = *(const float4*)(&src[(size_t)(r0 + rr) * Pc + pos0 + c4 * 4]);
        t[rr * 65 + c4 * 4 + 0] = v.x; t[rr * 65 + c4 * 4 + 1] = v.y;
        t[rr * 65 + c4 * 4 + 2] = v.z; t[rr * 65 + c4 * 4 + 3] = v.w;
      }
      __syncthreads();
#pragma unroll
      for (int it = 0; it < 2; ++it) {
        int lin = it * 256 + tid;
        int cc = lin >> 3, r8 = lin & 7;
        float m_ = which ? lmean[cc] : 0.f, rs_ = which ? lrstd[cc] : 1.f;
        ushort tmp[8];
#pragma unroll
        for (int j = 0; j < 8; ++j) {
          int ch = r8 * 8 + j;
          float x = t[ch * 65 + cc];
          float val = which ? (x - m_) * rs_ * gamma[r0 + ch] + beta[r0 + ch] : x;
          tmp[j] = f2bf(val);
        }
        *(uint4*)(&dst[(size_t)(pos0 + cc) * Cc + r0 + r8 * 8]) =
            *(const uint4*)tmp;
      }
      __syncthreads();
    }
  } else {
    int idx2 = idx - 144;
    if (idx2 < 40) {
      transpose_tile(Wv, WvT, Cc, INNERc, (idx2 / 8) * 64, (idx2 % 8) * 64,
                     tid, (float(*)[65])smem);
    } else if (idx2 < 80) {
      int i = idx2 - 40;
      transpose_tile(Wo, WoT, INNERc, Cc, (i / 5) * 64, (i % 5) * 64, tid,
                     (float(*)[65])smem);
    } else {
      int i = idx2 - 80;
      int c0 = (i % 5) * 64, h = (i / 5) % 8, zz = i / 40;
      const float* filt = zz ? dif : exf;
      const float* W = zz ? Wq : Wk;
      ushort* G = zz ? Gq : Gk;
      float (*ef)[66] = (float(*)[66])smem;
      float (*wk)[65] = (float(*)[65])(smem + 32 * 66);
      for (int l = tid; l < Fc * DHc; l += 256) {
        int f = l >> 6, d = l & 63;
        ef[f][d] = filt[(size_t)f * INNERc + h * 64 + d];
      }
      for (int l = tid; l < 64 * DHc; l += 256) {
        int cc = l >> 6, d = l & 63;
        wk[cc][d] = W[(size_t)(c0 + cc) * INNERc + h * 64 + d];
      }
      __syncthreads();
      int f = tid >> 3, cbase = tid & 7;
      float acc[8] = {};
#pragma unroll
      for (int d4 = 0; d4 < DHc; d4 += 4) {
        float4 a = *(const float4*)(&ef[f][d4]);
#pragma unroll
        for (int j = 0; j < 8; ++j) {
          float4 b = *(const float4*)(&wk[cbase + j * 8][d4]);
          acc[j] += a.x * b.x + a.y * b.y + a.z * b.z + a.w * b.w;
        }
      }
#pragma unroll
      for (int j = 0; j < 8; ++j)
        G[(size_t)(h * Fc + f) * Cc + c0 + cbase + j * 8] = f2bf(acc[j]);
    }
  }
}

// ---------------------------------------------------------------------------
// 2. Fused spatial attention chunk (V-projection fused). Writes per-chunk
//    partials svp/mj/lj ONLY — no cross-block sync (R7-proven form).
// ---------------------------------------------------------------------------
__global__ __launch_bounds__(256) void spatial_kernel(
    const ushort* __restrict__ Gk, const ushort* __restrict__ ehsT,
    const ushort* __restrict__ WvT, const float* __restrict__ scale_p,
    float* __restrict__ svp, float* __restrict__ mj, float* __restrict__ lj) {
  int c = blockIdx.x, h = blockIdx.y, b = blockIdx.z;
  int tid = threadIdx.x, lane = tid & 63, wv = tid >> 6;
  int l15 = lane & 15, kq = lane >> 4;
  int pos0 = c * CHUNK_P;
  int bh = b * HEADSc + h;
  float s = scale_p[0];

  __shared__ alignas(16) ushort As[96 * 64];
  __shared__ alignas(16) ushort Bs[128 * 64];
  __shared__ float Sq[32 * 132];
  __shared__ alignas(16) ushort P[32 * 136];
  __shared__ alignas(16) ushort Vs[64 * 136];

  const ushort* Av = WvT + (size_t)(h * 64) * Cc;
  const ushort* Ag = Gk + (size_t)(h * Fc) * Cc;
  const ushort* Bb = ehsT + ((size_t)b * Pc + pos0) * Cc;

  f32x4 acc[6][2] = {};
  for (int k0 = 0; k0 < Cc; k0 += 64) {
#pragma unroll
    for (int it = 0; it < 3; ++it) {
      int lin = it * 256 + tid;
      int row = lin >> 3, p = lin & 7;
      int lc = p ^ (row & 7);
      const ushort* sp = (row < 64) ? (Av + (size_t)row * Cc + k0 + lc * 8)
                                    : (Ag + (size_t)(row - 64) * Cc + k0 + lc * 8);
      *(uint4*)(&As[row * 64 + p * 8]) = *(const uint4*)sp;
    }
#pragma unroll
    for (int it = 0; it < 4; ++it) {
      int lin = it * 256 + tid;
      int row = lin >> 3, p = lin & 7;
      int lc = p ^ (row & 7);
      *(uint4*)(&Bs[row * 64 + p * 8]) =
          *(const uint4*)(Bb + (size_t)row * Cc + k0 + lc * 8);
    }
    __syncthreads();
#pragma unroll
    for (int ss = 0; ss < 2; ++ss) {
      bf16x8 af[6], bfr[2];
#pragma unroll
      for (int mt = 0; mt < 6; ++mt) {
        int m = mt * 16 + l15;
        int p = (ss * 4 + kq) ^ (m & 7);
        af[mt] = *(const bf16x8*)(&As[m * 64 + p * 8]);
      }
#pragma unroll
      for (int nt = 0; nt < 2; ++nt) {
        int n = wv * 32 + nt * 16 + l15;
        int p = (ss * 4 + kq) ^ (n & 7);
        bfr[nt] = *(const bf16x8*)(&Bs[n * 64 + p * 8]);
      }
#pragma unroll
      for (int mt = 0; mt < 6; ++mt)
#pragma unroll
        for (int nt = 0; nt < 2; ++nt)
          acc[mt][nt] = __builtin_amdgcn_mfma_f32_16x16x32_bf16(
              af[mt], bfr[nt], acc[mt][nt], 0, 0, 0);
    }
    __syncthreads();
  }
#pragma unroll
  for (int mt = 0; mt < 6; ++mt)
#pragma unroll
    for (int nt = 0; nt < 2; ++nt) {
      int col = wv * 32 + nt * 16 + l15;
#pragma unroll
      for (int r = 0; r < 4; ++r) {
        int row = mt * 16 + kq * 4 + r;
        if (mt < 4) Vs[row * 136 + col] = f2bf(acc[mt][nt][r]);
        else Sq[(row - 64) * 132 + col] = acc[mt][nt][r];
      }
    }
  __syncthreads();

  {
    int row = tid >> 3, sub = tid & 7;
    float vals[16];
    float m_ = -1e30f;
#pragma unroll
    for (int i = 0; i < 16; ++i) {
      vals[i] = s * Sq[row * 132 + sub * 16 + i];
      m_ = fmaxf(m_, vals[i]);
    }
    m_ = fmaxf(m_, __shfl_xor(m_, 1));
    m_ = fmaxf(m_, __shfl_xor(m_, 2));
    m_ = fmaxf(m_, __shfl_xor(m_, 4));
    float l_ = 0.f;
#pragma unroll
    for (int i = 0; i < 16; i += 2) {
      float e0 = __expf(vals[i] - m_);
      float e1 = __expf(vals[i + 1] - m_);
      l_ += e0 + e1;
      uint pk = (uint)f2bf(e0) | ((uint)f2bf(e1) << 16);
      *(uint*)(&P[row * 136 + sub * 16 + i]) = pk;
    }
    l_ += __shfl_xor(l_, 1);
    l_ += __shfl_xor(l_, 2);
    l_ += __shfl_xor(l_, 4);
    if (sub == 0) {
      mj[((size_t)c * 16 + bh) * Fc + row] = m_;
      lj[((size_t)c * 16 + bh) * Fc + row] = l_;
    }
  }
  __syncthreads();

  f32x4 acc2[2] = {};
#pragma unroll
  for (int ss = 0; ss < 4; ++ss) {
    bf16x8 af[2];
#pragma unroll
    for (int mt = 0; mt < 2; ++mt)
      af[mt] = *(const bf16x8*)(&P[(mt * 16 + l15) * 136 + ss * 32 + kq * 8]);
    bf16x8 bfr = *(const bf16x8*)(&Vs[(wv * 16 + l15) * 136 + ss * 32 + kq * 8]);
#pragma unroll
    for (int mt = 0; mt < 2; ++mt)
      acc2[mt] = __builtin_amdgcn_mfma_f32_16x16x32_bf16(af[mt], bfr, acc2[mt],
                                                         0, 0, 0);
  }
  float* op = svp + ((size_t)c * 16 + bh) * (Fc * DHc);
#pragma unroll
  for (int mt = 0; mt < 2; ++mt)
#pragma unroll
    for (int r = 0; r < 4; ++r)
      op[(mt * 16 + kq * 4 + r) * DHc + wv * 16 + l15] = acc2[mt][r];
}

// ---------------------------------------------------------------------------
// 3. Fused channel attention -> OAT. The online-softmax merge of the 18
//    spatial chunks (formerly sv_reduce) is computed INLINE per block for its
//    2 heads — kernel-boundary ordering makes it safe, no atomics needed.
// ---------------------------------------------------------------------------
__global__ __launch_bounds__(256) void channel_kernel(
    const ushort* __restrict__ Gq, const ushort* __restrict__ hsT,
    const float* __restrict__ svp, const float* __restrict__ mj,
    const float* __restrict__ lj, const float* __restrict__ scale_p,
    ushort* __restrict__ OAT) {
  int pb = blockIdx.x, hp = blockIdx.y, b = blockIdx.z;
  int pos0 = pb * 64;
  int tid = threadIdx.x, lane = tid & 63, wv = tid >> 6;
  int l15 = lane & 15, kq = lane >> 4;
  float s = scale_p[0];

  __shared__ alignas(16) ushort Aq[2][32 * 64];
  __shared__ alignas(16) ushort Bs[64 * 64];
  __shared__ float SO[64 * 68];
  __shared__ alignas(16) ushort Pt[64 * 40];
  __shared__ alignas(16) ushort svs[64 * 40];
  __shared__ float red[4 * 64];
  __shared__ float wgt[Fc * CHUNKS];

  f32x4 acc[2][2] = {};
  const ushort* Bb = hsT + ((size_t)b * Pc + pos0) * Cc;
  for (int k0 = 0; k0 < Cc; k0 += 64) {
#pragma unroll
    for (int it = 0; it < 2; ++it) {
      int lin = it * 256 + tid;
      int hh = lin >> 8, row = (lin >> 3) & 31, p = lin & 7;
      int lc = p ^ (row & 7);
      *(uint4*)(&Aq[hh][row * 64 + p * 8]) = *(const uint4*)(
          Gq + (size_t)((hp * 2 + hh) * Fc + row) * Cc + k0 + lc * 8);
    }
#pragma unroll
    for (int it = 0; it < 2; ++it) {
      int lin = it * 256 + tid;
      int row = lin >> 3, p = lin & 7;
      int lc = p ^ (row & 7);
      *(uint4*)(&Bs[row * 64 + p * 8]) =
          *(const uint4*)(Bb + (size_t)row * Cc + k0 + lc * 8);
    }
    __syncthreads();
#pragma unroll
    for (int ss = 0; ss < 2; ++ss) {
      int n = wv * 16 + l15;
      int pb_ = (ss * 4 + kq) ^ (n & 7);
      bf16x8 bfr = *(const bf16x8*)(&Bs[n * 64 + pb_ * 8]);
#pragma unroll
      for (int hh = 0; hh < 2; ++hh)
#pragma unroll
        for (int mt = 0; mt < 2; ++mt) {
          int m = mt * 16 + l15;
          int pa = (ss * 4 + kq) ^ (m & 7);
          bf16x8 af = *(const bf16x8*)(&Aq[hh][m * 64 + pa * 8]);
          acc[hh][mt] = __builtin_amdgcn_mfma_f32_16x16x32_bf16(
              af, bfr, acc[hh][mt], 0, 0, 0);
        }
    }
    __syncthreads();
  }

  for (int hh = 0; hh < 2; ++hh) {
    int h = hp * 2 + hh;
    int bh = b * HEADSc + h;
    // scores -> LDS; in parallel, 32 threads build the per-f chunk weights
#pragma unroll
    for (int mt = 0; mt < 2; ++mt)
#pragma unroll
      for (int r = 0; r < 4; ++r)
        SO[(mt * 16 + kq * 4 + r) * 68 + wv * 16 + l15] = acc[hh][mt][r];
    if (tid < Fc) {
      int f = tid;
      float m = -1e30f;
#pragma unroll
      for (int cc = 0; cc < CHUNKS; ++cc)
        m = fmaxf(m, mj[((size_t)cc * 16 + bh) * Fc + f]);
      float w[CHUNKS];
      float Ltot = 0.f;
#pragma unroll
      for (int cc = 0; cc < CHUNKS; ++cc) {
        w[cc] = __expf(mj[((size_t)cc * 16 + bh) * Fc + f] - m);
        Ltot += w[cc] * lj[((size_t)cc * 16 + bh) * Fc + f];
      }
      float inv = 1.f / Ltot;
#pragma unroll
      for (int cc = 0; cc < CHUNKS; ++cc) wgt[f * CHUNKS + cc] = w[cc] * inv;
    }
    __syncthreads();
    // inline sv_reduce: svs[d][f] = sum_cc wgt[f][cc] * svp[cc][bh][f][d]
#pragma unroll
    for (int it = 0; it < 8; ++it) {
      int lin = it * 256 + tid;
      int f = lin >> 6, d = lin & 63;
      const float* sp = svp + (size_t)bh * (Fc * DHc) + f * DHc + d;
      float a = 0.f;
#pragma unroll
      for (int cc = 0; cc < CHUNKS; ++cc)
        a += wgt[f * CHUNKS + cc] * sp[(size_t)cc * 16 * (Fc * DHc)];
      svs[d * 40 + f] = f2bf(a);
    }
    // softmax over f per pos
    {
      int pos = tid & 63, g = tid >> 6;
      float v8[8];
      float pm = -1e30f;
#pragma unroll
      for (int i = 0; i < 8; ++i) {
        v8[i] = s * SO[(g * 8 + i) * 68 + pos];
        pm = fmaxf(pm, v8[i]);
      }
      red[g * 64 + pos] = pm;
      __syncthreads();
      float m_ = fmaxf(fmaxf(red[pos], red[64 + pos]),
                       fmaxf(red[128 + pos], red[192 + pos]));
      __syncthreads();
      float ps = 0.f;
#pragma unroll
      for (int i = 0; i < 8; ++i) {
        v8[i] = __expf(v8[i] - m_);
        ps += v8[i];
      }
      red[g * 64 + pos] = ps;
      __syncthreads();
      float inv = 1.f / (red[pos] + red[64 + pos] + red[128 + pos] +
                         red[192 + pos]);
#pragma unroll
      for (int i = 0; i < 8; i += 2) {
        uint pk = (uint)f2bf(v8[i] * inv) | ((uint)f2bf(v8[i + 1] * inv) << 16);
        *(uint*)(&Pt[pos * 40 + g * 8 + i]) = pk;
      }
    }
    __syncthreads();
    // O = Pt(64x32) . svs^T
    {
      bf16x8 b_ = *(const bf16x8*)(&svs[(wv * 16 + l15) * 40 + kq * 8]);
      f32x4 acc3[4];
#pragma unroll
      for (int mt = 0; mt < 4; ++mt) {
        bf16x8 a_ = *(const bf16x8*)(&Pt[(mt * 16 + l15) * 40 + kq * 8]);
        f32x4 z = {0.f, 0.f, 0.f, 0.f};
        acc3[mt] = __builtin_amdgcn_mfma_f32_16x16x32_bf16(a_, b_, z, 0, 0, 0);
      }
#pragma unroll
      for (int mt = 0; mt < 4; ++mt)
#pragma unroll
        for (int r = 0; r < 4; ++r)
          SO[(mt * 16 + kq * 4 + r) * 68 + wv * 16 + l15] = acc3[mt][r];
    }
    __syncthreads();
#pragma unroll
    for (int it = 0; it < 2; ++it) {
      int lin = it * 256 + tid;
      int p = lin >> 3, c8 = lin & 7;
      ushort tmp[8];
#pragma unroll
      for (int j = 0; j < 8; ++j) tmp[j] = f2bf(SO[p * 68 + c8 * 8 + j]);
      *(uint4*)(&OAT[((size_t)b * Pc + pos0 + p) * INNERc + h * 64 + c8 * 8]) =
          *(const uint4*)tmp;
    }
    __syncthreads();
  }
}

// ---------------------------------------------------------------------------
// 4. Final GEMM: out = WoT . OAT + bias + s*res. K=512.
// ---------------------------------------------------------------------------
__global__ __launch_bounds__(256) void gemm_mfma_kernel(
    const ushort* __restrict__ A, const ushort* __restrict__ Bt,
    float* __restrict__ Out, int K, int Mdim,
    const float* __restrict__ bias, const float* __restrict__ res,
    const float* __restrict__ scale_p) {
  int b = blockIdx.z;
  int n0 = blockIdx.x * 128, m0 = blockIdx.y * 64;
  int tid = threadIdx.x, lane = tid & 63, wv = tid >> 6;
  int l15 = lane & 15, kq = lane >> 4;
  __shared__ alignas(16) ushort As[64 * 64];
  __shared__ alignas(16) ushort Bs[128 * 64];
  const ushort* Ab = A + (size_t)m0 * K;
  const ushort* Bb = Bt + ((size_t)b * Pc + n0) * K;

  f32x4 acc[4][2] = {};
  for (int k0 = 0; k0 < K; k0 += 64) {
#pragma unroll
    for (int it = 0; it < 2; ++it) {
      int lin = it * 256 + tid;
      int row = lin >> 3, p = lin & 7;
      int lc = p ^ (row & 7);
      *(uint4*)(&As[row * 64 + p * 8]) =
          *(const uint4*)(Ab + (size_t)row * K + k0 + lc * 8);
    }
#pragma unroll
    for (int it = 0; it < 4; ++it) {
      int lin = it * 256 + tid;
      int row = lin >> 3, p = lin & 7;
      int lc = p ^ (row & 7);
      *(uint4*)(&Bs[row * 64 + p * 8]) =
          *(const uint4*)(Bb + (size_t)row * K + k0 + lc * 8);
    }
    __syncthreads();
#pragma unroll
    for (int ss = 0; ss < 2; ++ss) {
      bf16x8 af[4], bfr[2];
#pragma unroll
      for (int mt = 0; mt < 4; ++mt) {
        int m = mt * 16 + l15;
        int p = (ss * 4 + kq) ^ (m & 7);
        af[mt] = *(const bf16x8*)(&As[m * 64 + p * 8]);
      }
#pragma unroll
      for (int nt = 0; nt < 2; ++nt) {
        int n = wv * 32 + nt * 16 + l15;
        int p = (ss * 4 + kq) ^ (n & 7);
        bfr[nt] = *(const bf16x8*)(&Bs[n * 64 + p * 8]);
      }
#pragma unroll
      for (int mt = 0; mt < 4; ++mt)
#pragma unroll
        for (int nt = 0; nt < 2; ++nt)
          acc[mt][nt] = __builtin_amdgcn_mfma_f32_16x16x32_bf16(
              af[mt], bfr[nt], acc[mt][nt], 0, 0, 0);
    }
    __syncthreads();
  }
  float s = scale_p[0];
  float* Ob = Out + ((size_t)b * Mdim + m0) * Pc + n0;
  const float* rb = res + ((size_t)b * Mdim + m0) * Pc + n0;
#pragma unroll
  for (int mt = 0; mt < 4; ++mt)
#pragma unroll
    for (int nt = 0; nt < 2; ++nt) {
      int ncol = wv * 32 + nt * 16 + l15;
#pragma unroll
      for (int r = 0; r < 4; ++r) {
        int m = mt * 16 + kq * 4 + r;
        Ob[(size_t)m * Pc + ncol] =
            acc[mt][nt][r] + bias[m0 + m] + s * rb[(size_t)m * Pc + ncol];
      }
    }
}

// ---------------------------------------------------------------------------
extern "C" void kernel_launch(void* const* d_in, const int* in_sizes, int n_in,
                              void* d_out, int out_size, void* d_ws, size_t ws_size,
                              hipStream_t stream) {
  const float* hs    = (const float*)d_in[0];
  const float* ehs   = (const float*)d_in[1];
  const float* Wq    = (const float*)d_in[2];
  const float* Wk    = (const float*)d_in[3];
  const float* Wv    = (const float*)d_in[4];
  const float* Wo    = (const float*)d_in[5];
  const float* bo    = (const float*)d_in[6];
  const float* gamma = (const float*)d_in[7];
  const float* beta  = (const float*)d_in[8];
  const float* exf   = (const float*)d_in[9];
  const float* dif   = (const float*)d_in[10];
  const float* scale = (const float*)d_in[11];
  float* out = (float*)d_out;

  float* ws = (float*)d_ws;
  float* svp = ws;                         //   589,824 f
  float* mj  = svp + 589824;               //     9,216 f
  float* lj  = mj + 9216;                  //     9,216 f
  ushort* hsT  = (ushort*)(lj + 9216);     // 1,474,560 us
  ushort* ehsT = hsT + 1474560;            // 1,474,560 us
  ushort* WvT  = ehsT + 1474560;           //   163,840 us
  ushort* WoT  = WvT + 163840;             //   163,840 us
  ushort* Gk   = WoT + 163840;             //    81,920 us
  ushort* Gq   = Gk + 81920;               //    81,920 us
  ushort* OAT  = Gq + 81920;               // 2,359,296 us

  prep_all_kernel<<<dim3(304), dim3(256), 0, stream>>>(
      hs, ehs, gamma, beta, Wv, Wo, exf, Wk, dif, Wq,
      hsT, ehsT, WvT, WoT, Gk, Gq);
  spatial_kernel<<<dim3(CHUNKS, HEADSc, Bc), dim3(256), 0, stream>>>(
      Gk, ehsT, WvT, scale, svp, mj, lj);
  channel_kernel<<<dim3(Pc / 64, HEADSc / 2, Bc), dim3(256), 0, stream>>>(
      Gq, hsT, svp, mj, lj, scale, OAT);
  gemm_mfma_kernel<<<dim3(Pc / 128, Cc / 64, Bc), dim3(256), 0, stream>>>(
      WoT, OAT, out, INNERc, Cc, bo, hs, scale);
}